// Round 2
// baseline (444.628 us; speedup 1.0000x reference)
//
#include <hip/hip_runtime.h>

#define HH 512
#define WW 512
#define NCH 3
#define NBATCH 16
#define NIMG (NBATCH*NCH)     // 48
#define CHUNK 32              // output rows per wave
#define NCHUNK (HH/CHUNK)     // 16
#define NSTRIP 4              // 128-col strips
#define SW 128
#define SLOTS 140             // 138 used: cols c0-5 .. c0+132 at slot = col-c0+5
#define NT 64                 // one wave per block -> no barriers anywhere

static __device__ __forceinline__ float2 f2add(float2 a, float2 b){ return make_float2(a.x+b.x, a.y+b.y); }
static __device__ __forceinline__ float2 f2sub(float2 a, float2 b){ return make_float2(a.x-b.x, a.y-b.y); }

struct RowData { float4 m; float2 h; };

__global__ __launch_bounds__(NT, 3) void ssim_main(
    const float* __restrict__ pred, const float* __restrict__ targ,
    float* __restrict__ ws)
{
  // wave-private row buffer: slot s holds (x,y) of col c0+s-5.
  // Same-wave LDS ops are in-order -> no __syncthreads needed; compiler
  // ordering pinned by zero-cost asm memory clobbers.
  __shared__ __align__(16) float2 rowb[SLOTS];

  const int l = threadIdx.x;
  const int blk = blockIdx.x;
  const int img = blk >> 6;              // / (NCHUNK*NSTRIP)
  const int rem = blk & 63;
  const int chunk = rem >> 2;
  const int strip = rem & 3;
  const int b = img / NCH;

  const int r0 = chunk*CHUNK - 5;        // first input row
  const int c0 = strip*SW;

  // zero the pad slots once (image-edge strips keep them zero forever)
  if (l < 10) rowb[(l < 5) ? l : (128 + l)] = make_float2(0.f, 0.f);
  asm volatile("" ::: "memory");

  const size_t ib = (size_t)img * (size_t)(HH*WW);
  const float* pp = pred + ib;
  const float* tp = targ + ib;

  const int cm = c0 + 2*l;               // this lane's 2 main cols
  const int h  = l - 54;                 // halo id 0..9 on lanes 54..63
  const int ch = (h < 5) ? (c0 - 5 + h) : (c0 + 123 + h);   // halo col
  const bool hval = (l >= 54) && ((unsigned)ch < (unsigned)WW);
  const int hs = (h < 5) ? h : (128 + h);                    // halo slot

  auto loadrow = [&](int it) -> RowData {
    RowData d;
    const int r = r0 + it;
    if ((unsigned)r < (unsigned)HH) {    // wave-uniform branch
      const size_t ro = (size_t)r * WW;
      const float2 x = *(const float2*)(pp + ro + cm);
      const float2 y = *(const float2*)(tp + ro + cm);
      d.m = make_float4(x.x, x.y, y.x, y.y);
      if (hval) d.h = make_float2(pp[ro + ch], tp[ro + ch]);
      else      d.h = make_float2(0.f, 0.f);
    } else {
      d.m = make_float4(0.f, 0.f, 0.f, 0.f);
      d.h = make_float2(0.f, 0.f);
    }
    return d;
  };

  // vertical ring of horizontal sums: 11 rows x 4 quantities x 2 cols
  // (x, y, xy, ss=xx+yy -- SSIM only needs sigma_x+sigma_y summed)
  float2 rgx[11], rgy[11], rgxy[11], rgss[11];
  float2 vx = make_float2(0.f,0.f), vy = vx, vxy = vx, vss = vx;
  float acc = 0.f;

  RowData cur = loadrow(0);
  RowData nxt = loadrow(1);

  constexpr float c1 = 0.0001f, c2 = 0.0009f, inv121 = 1.0f/121.0f;

  auto ssim1 = [&](float Sx, float Sy, float Sxy, float Sss) -> float {
    const float mux = Sx*inv121, muy = Sy*inv121;
    const float muxy = mux*muy;
    const float m2   = fmaf(mux, mux, muy*muy);
    const float sgxy = fmaf(Sxy, inv121, -muxy);
    const float sgss = fmaf(Sss, inv121, -m2);
    const float num = fmaf(2.f, muxy, c1) * fmaf(2.f, sgxy, c2);
    const float den = (m2 + c1) * (sgss + c2);
    const float s = num * __builtin_amdgcn_rcpf(den);
    return fminf(fmaxf(s, 0.f), 1.f);
  };

  auto body = [&](int it, int slot, bool dosub, bool doemit) {
    // stage row it (interleaved (x,y) so taps read as aligned float4)
    rowb[5 + 2*l] = make_float2(cur.m.x, cur.m.z);
    rowb[6 + 2*l] = make_float2(cur.m.y, cur.m.w);
    if (hval) rowb[hs] = cur.h;
    cur = nxt;
    nxt = loadrow(it + 2);               // prefetch 2 rows ahead
    asm volatile("" ::: "memory");       // pin writes before reads

    // taps p=0..11 <-> local cols 2l-5 .. 2l+6 <-> slots 2l .. 2l+11 (16B-aligned)
    const float4* tb = (const float4*)(rowb + 2*l);
    float sx=0.f, sy=0.f, sxy=0.f, sss=0.f;
    float x0=0.f, y0=0.f, x11=0.f, y11=0.f;
    #pragma unroll
    for (int j = 0; j < 6; ++j) {
      const float4 v = tb[j];            // (x[p], y[p], x[p+1], y[p+1]), p=2j
      if (j == 0) { x0 = v.x; y0 = v.y; }
      sx += v.x; sy += v.y;
      sxy = fmaf(v.x, v.y, sxy);
      sss = fmaf(v.x, v.x, sss);
      sss = fmaf(v.y, v.y, sss);
      if (j < 5) {
        sx += v.z; sy += v.w;
        sxy = fmaf(v.z, v.w, sxy);
        sss = fmaf(v.z, v.z, sss);
        sss = fmaf(v.w, v.w, sss);
      } else { x11 = v.z; y11 = v.w; }
    }
    asm volatile("" ::: "memory");       // pin reads before next row's writes

    // col0 window = p0..p10 ; col1 = col0 - p0 + p11
    const float2 hx  = make_float2(sx,  sx - x0 + x11);
    const float2 hy  = make_float2(sy,  sy - y0 + y11);
    const float2 hxy = make_float2(sxy, fmaf(x11, y11, fmaf(-x0, y0, sxy)));
    const float2 hss = make_float2(sss,
        fmaf(x11, x11, fmaf(y11, y11, fmaf(-x0, x0, fmaf(-y0, y0, sss)))));

    if (dosub) {
      vx  = f2sub(vx,  rgx[slot]);  vy  = f2sub(vy,  rgy[slot]);
      vxy = f2sub(vxy, rgxy[slot]); vss = f2sub(vss, rgss[slot]);
    }
    rgx[slot] = hx; rgy[slot] = hy; rgxy[slot] = hxy; rgss[slot] = hss;
    vx  = f2add(vx,  hx);  vy  = f2add(vy,  hy);
    vxy = f2add(vxy, hxy); vss = f2add(vss, hss);

    if (doemit) {
      acc += ssim1(vx.x, vy.x, vxy.x, vss.x);
      acc += ssim1(vx.y, vy.y, vxy.y, vss.y);
    }
  };

  // 42 input rows: warmup 11 (first emit at it=10), steady 2x11, tail 9
  #pragma unroll
  for (int u = 0; u < 11; ++u) body(u, u, false, u == 10);
  for (int g = 0; g < 2; ++g) {
    #pragma unroll
    for (int u = 0; u < 11; ++u) body(11 + 11*g + u, u, true, true);
  }
  #pragma unroll
  for (int u = 0; u < 9; ++u) body(33 + u, u, true, true);

  // wave reduction -> one atomic per wave (no cross-wave step needed)
  #pragma unroll
  for (int off = 32; off > 0; off >>= 1) acc += __shfl_down(acc, off, 64);
  if (l == 0) atomicAdd(&ws[b], acc);
}

__global__ void ssim_final(const float* __restrict__ ws, float* __restrict__ out) {
  const int i = threadIdx.x;
  if (i < NBATCH) out[i] = 1.0f - ws[i] * (1.0f / (float)(NCH*HH*WW));
}

extern "C" void kernel_launch(void* const* d_in, const int* in_sizes, int n_in,
                              void* d_out, int out_size, void* d_ws, size_t ws_size,
                              hipStream_t stream) {
  const float* pred = (const float*)d_in[0];
  const float* targ = (const float*)d_in[1];
  float* out = (float*)d_out;
  float* ws  = (float*)d_ws;
  hipMemsetAsync(ws, 0, NBATCH * sizeof(float), stream);
  ssim_main<<<dim3(NIMG*NCHUNK*NSTRIP), dim3(NT), 0, stream>>>(pred, targ, ws);
  ssim_final<<<dim3(1), dim3(64), 0, stream>>>(ws, out);
}

// Round 3
// 369.576 us; speedup vs baseline: 1.2031x; 1.2031x over previous
//
#include <hip/hip_runtime.h>

#define HH 512
#define WW 512
#define NCH 3
#define NBATCH 16
#define NIMG (NBATCH*NCH)     // 48
#define CHUNK 32              // output rows per wave
#define NCHUNK (HH/CHUNK)     // 16
#define NSTRIP 4              // 128-col strips
#define SW 128
#define SLOTS 140             // 138 used: cols c0-5 .. c0+132 at slot = col-c0+5
#define NT 64                 // one wave per block -> no barriers anywhere

static __device__ __forceinline__ float2 f2add(float2 a, float2 b){ return make_float2(a.x+b.x, a.y+b.y); }
static __device__ __forceinline__ float2 f2sub(float2 a, float2 b){ return make_float2(a.x-b.x, a.y-b.y); }

struct RowData { float4 m; float2 h; };

// waves_per_eu(2,2): pin allocator to exactly 2 waves/SIMD -> 256-VGPR budget.
// R2 lesson: __launch_bounds__(64,3) let the heuristic target 6 waves/EU
// (84 VGPRs) and spill the 88-float ring to scratch (619 MB WRITE_SIZE).
__global__ __launch_bounds__(NT) __attribute__((amdgpu_waves_per_eu(2, 2)))
void ssim_main(
    const float* __restrict__ pred, const float* __restrict__ targ,
    float* __restrict__ ws)
{
  // wave-private row buffer: slot s holds (x,y) of col c0+s-5.
  // Same-wave LDS ops are in-order -> no __syncthreads needed; compiler
  // ordering pinned by zero-cost asm memory clobbers.
  __shared__ __align__(16) float2 rowb[SLOTS];

  const int l = threadIdx.x;
  const int blk = blockIdx.x;
  const int img = blk >> 6;              // / (NCHUNK*NSTRIP)
  const int rem = blk & 63;
  const int chunk = rem >> 2;
  const int strip = rem & 3;
  const int b = img / NCH;

  const int r0 = chunk*CHUNK - 5;        // first input row
  const int c0 = strip*SW;

  // zero the pad slots once (image-edge strips keep them zero forever)
  if (l < 10) rowb[(l < 5) ? l : (128 + l)] = make_float2(0.f, 0.f);
  asm volatile("" ::: "memory");

  const size_t ib = (size_t)img * (size_t)(HH*WW);
  const float* pp = pred + ib;
  const float* tp = targ + ib;

  const int cm = c0 + 2*l;               // this lane's 2 main cols
  const int h  = l - 54;                 // halo id 0..9 on lanes 54..63
  const int ch = (h < 5) ? (c0 - 5 + h) : (c0 + 123 + h);   // halo col
  const bool hval = (l >= 54) && ((unsigned)ch < (unsigned)WW);
  const int hs = (h < 5) ? h : (128 + h);                    // halo slot

  auto loadrow = [&](int it) -> RowData {
    RowData d;
    const int r = r0 + it;
    if ((unsigned)r < (unsigned)HH) {    // wave-uniform branch
      const size_t ro = (size_t)r * WW;
      const float2 x = *(const float2*)(pp + ro + cm);
      const float2 y = *(const float2*)(tp + ro + cm);
      d.m = make_float4(x.x, x.y, y.x, y.y);
      if (hval) d.h = make_float2(pp[ro + ch], tp[ro + ch]);
      else      d.h = make_float2(0.f, 0.f);
    } else {
      d.m = make_float4(0.f, 0.f, 0.f, 0.f);
      d.h = make_float2(0.f, 0.f);
    }
    return d;
  };

  // vertical ring of horizontal sums: 11 rows x 4 quantities x 2 cols
  // (x, y, xy, ss=xx+yy -- SSIM only needs sigma_x+sigma_y summed)
  float2 rgx[11], rgy[11], rgxy[11], rgss[11];
  float2 vx = make_float2(0.f,0.f), vy = vx, vxy = vx, vss = vx;
  float acc = 0.f;

  RowData cur = loadrow(0);
  RowData nxt = loadrow(1);

  constexpr float c1 = 0.0001f, c2 = 0.0009f, inv121 = 1.0f/121.0f;

  auto ssim1 = [&](float Sx, float Sy, float Sxy, float Sss) -> float {
    const float mux = Sx*inv121, muy = Sy*inv121;
    const float muxy = mux*muy;
    const float m2   = fmaf(mux, mux, muy*muy);
    const float sgxy = fmaf(Sxy, inv121, -muxy);
    const float sgss = fmaf(Sss, inv121, -m2);
    const float num = fmaf(2.f, muxy, c1) * fmaf(2.f, sgxy, c2);
    const float den = (m2 + c1) * (sgss + c2);
    const float s = num * __builtin_amdgcn_rcpf(den);
    return fminf(fmaxf(s, 0.f), 1.f);
  };

  auto body = [&](int it, int slot, bool dosub, bool doemit) {
    // stage row it (interleaved (x,y) so taps read as aligned float4)
    rowb[5 + 2*l] = make_float2(cur.m.x, cur.m.z);
    rowb[6 + 2*l] = make_float2(cur.m.y, cur.m.w);
    if (hval) rowb[hs] = cur.h;
    cur = nxt;
    nxt = loadrow(it + 2);               // prefetch 2 rows ahead
    asm volatile("" ::: "memory");       // pin writes before reads

    // taps p=0..11 <-> local cols 2l-5 .. 2l+6 <-> slots 2l .. 2l+11 (16B-aligned)
    const float4* tb = (const float4*)(rowb + 2*l);
    float sx=0.f, sy=0.f, sxy=0.f, sss=0.f;
    float x0=0.f, y0=0.f, x11=0.f, y11=0.f;
    #pragma unroll
    for (int j = 0; j < 6; ++j) {
      const float4 v = tb[j];            // (x[p], y[p], x[p+1], y[p+1]), p=2j
      if (j == 0) { x0 = v.x; y0 = v.y; }
      sx += v.x; sy += v.y;
      sxy = fmaf(v.x, v.y, sxy);
      sss = fmaf(v.x, v.x, sss);
      sss = fmaf(v.y, v.y, sss);
      if (j < 5) {
        sx += v.z; sy += v.w;
        sxy = fmaf(v.z, v.w, sxy);
        sss = fmaf(v.z, v.z, sss);
        sss = fmaf(v.w, v.w, sss);
      } else { x11 = v.z; y11 = v.w; }
    }
    asm volatile("" ::: "memory");       // pin reads before next row's writes

    // col0 window = p0..p10 ; col1 = col0 - p0 + p11
    const float2 hx  = make_float2(sx,  sx - x0 + x11);
    const float2 hy  = make_float2(sy,  sy - y0 + y11);
    const float2 hxy = make_float2(sxy, fmaf(x11, y11, fmaf(-x0, y0, sxy)));
    const float2 hss = make_float2(sss,
        fmaf(x11, x11, fmaf(y11, y11, fmaf(-x0, x0, fmaf(-y0, y0, sss)))));

    if (dosub) {
      vx  = f2sub(vx,  rgx[slot]);  vy  = f2sub(vy,  rgy[slot]);
      vxy = f2sub(vxy, rgxy[slot]); vss = f2sub(vss, rgss[slot]);
    }
    rgx[slot] = hx; rgy[slot] = hy; rgxy[slot] = hxy; rgss[slot] = hss;
    vx  = f2add(vx,  hx);  vy  = f2add(vy,  hy);
    vxy = f2add(vxy, hxy); vss = f2add(vss, hss);

    if (doemit) {
      acc += ssim1(vx.x, vy.x, vxy.x, vss.x);
      acc += ssim1(vx.y, vy.y, vxy.y, vss.y);
    }
  };

  // 42 input rows: warmup 11 (first emit at it=10), steady 2x11, tail 9
  #pragma unroll
  for (int u = 0; u < 11; ++u) body(u, u, false, u == 10);
  for (int g = 0; g < 2; ++g) {
    #pragma unroll
    for (int u = 0; u < 11; ++u) body(11 + 11*g + u, u, true, true);
  }
  #pragma unroll
  for (int u = 0; u < 9; ++u) body(33 + u, u, true, true);

  // wave reduction -> one atomic per wave (no cross-wave step needed)
  #pragma unroll
  for (int off = 32; off > 0; off >>= 1) acc += __shfl_down(acc, off, 64);
  if (l == 0) atomicAdd(&ws[b], acc);
}

__global__ void ssim_final(const float* __restrict__ ws, float* __restrict__ out) {
  const int i = threadIdx.x;
  if (i < NBATCH) out[i] = 1.0f - ws[i] * (1.0f / (float)(NCH*HH*WW));
}

extern "C" void kernel_launch(void* const* d_in, const int* in_sizes, int n_in,
                              void* d_out, int out_size, void* d_ws, size_t ws_size,
                              hipStream_t stream) {
  const float* pred = (const float*)d_in[0];
  const float* targ = (const float*)d_in[1];
  float* out = (float*)d_out;
  float* ws  = (float*)d_ws;
  hipMemsetAsync(ws, 0, NBATCH * sizeof(float), stream);
  ssim_main<<<dim3(NIMG*NCHUNK*NSTRIP), dim3(NT), 0, stream>>>(pred, targ, ws);
  ssim_final<<<dim3(1), dim3(64), 0, stream>>>(ws, out);
}

// Round 4
// 173.692 us; speedup vs baseline: 2.5599x; 2.1278x over previous
//
#include <hip/hip_runtime.h>

#define HH 512
#define WW 512
#define NCH 3
#define NBATCH 16
#define NIMG (NBATCH*NCH)     // 48
#define CHUNK 64              // output rows per wave
#define NCHUNK (HH/CHUNK)     // 8
#define NSTRIP 4              // 128-col strips
#define SW 128
#define SLOTS 140             // cols c0-5 .. c0+132 at slot = col-c0+5
#define NT 64                 // one wave per block -> no barriers anywhere

static __device__ __forceinline__ float2 f2add(float2 a, float2 b){ return make_float2(a.x+b.x, a.y+b.y); }

struct RowData { float4 m; float2 h; };

// R2/R3 lesson: the 88-float register ring spills no matter how we beg the
// allocator (waves_per_eu pins ignored; 286-619 MB scratch traffic). Fix:
// ring lives in LDS (lane-private slots, conflict-free 16B stride). 23.6 KB
// LDS also caps occupancy at 6 blocks/CU, which relaxes the RA's occupancy
// target -> no VGPR squeeze. Grid 1536 = 6/CU = fully co-resident.
__global__ __launch_bounds__(NT) void ssim_main(
    const float* __restrict__ pred, const float* __restrict__ targ,
    float* __restrict__ ws)
{
  // row staging: slot s holds (x,y) of col c0+s-5 (same-wave LDS is in-order,
  // no barriers; compiler ordering pinned with asm memory clobbers)
  __shared__ __align__(16) float2 rowb[SLOTS];
  // vertical ring of horizontal sums: ring0 = col0 (hx,hy,hxy,hss), ring1 = col1
  __shared__ __align__(16) float4 ring0[11][NT];
  __shared__ __align__(16) float4 ring1[11][NT];

  const int l = threadIdx.x;
  const int blk = blockIdx.x;
  const int img = blk >> 5;              // / (NCHUNK*NSTRIP)
  const int rem = blk & 31;
  const int chunk = rem >> 2;
  const int strip = rem & 3;
  const int b = img / NCH;

  const int r0 = chunk*CHUNK - 5;        // first input row
  const int c0 = strip*SW;

  // zero the pad slots once (image-edge strips keep them zero forever)
  if (l < 10) rowb[(l < 5) ? l : (128 + l)] = make_float2(0.f, 0.f);
  asm volatile("" ::: "memory");

  const size_t ib = (size_t)img * (size_t)(HH*WW);
  const float* pp = pred + ib;
  const float* tp = targ + ib;

  const int cm = c0 + 2*l;               // this lane's 2 main cols
  const int h  = l - 54;                 // halo id 0..9 on lanes 54..63
  const int ch = (h < 5) ? (c0 - 5 + h) : (c0 + 123 + h);   // halo col
  const bool hval = (l >= 54) && ((unsigned)ch < (unsigned)WW);
  const int hs = (h < 5) ? h : (128 + h);                    // halo slot

  auto loadrow = [&](int it) -> RowData {
    RowData d;
    const int r = r0 + it;
    if ((unsigned)r < (unsigned)HH) {    // wave-uniform branch
      const size_t ro = (size_t)r * WW;
      const float2 x = *(const float2*)(pp + ro + cm);
      const float2 y = *(const float2*)(tp + ro + cm);
      d.m = make_float4(x.x, x.y, y.x, y.y);
      if (hval) d.h = make_float2(pp[ro + ch], tp[ro + ch]);
      else      d.h = make_float2(0.f, 0.f);
    } else {
      d.m = make_float4(0.f, 0.f, 0.f, 0.f);
      d.h = make_float2(0.f, 0.f);
    }
    return d;
  };

  // vertical running sums: (x, y, xy, ss=xx+yy) per col — registers
  float2 vx = make_float2(0.f,0.f), vy = vx, vxy = vx, vss = vx;
  float acc = 0.f;

  // 3-deep global prefetch (~900 cyc lead = HBM miss latency)
  RowData cur = loadrow(0);
  RowData nxt = loadrow(1);
  RowData nx2 = loadrow(2);

  constexpr float c1 = 0.0001f, c2 = 0.0009f, inv121 = 1.0f/121.0f;

  auto ssim1 = [&](float Sx, float Sy, float Sxy, float Sss) -> float {
    const float mux = Sx*inv121, muy = Sy*inv121;
    const float muxy = mux*muy;
    const float m2   = fmaf(mux, mux, muy*muy);
    const float sgxy = fmaf(Sxy, inv121, -muxy);
    const float sgss = fmaf(Sss, inv121, -m2);
    const float num = fmaf(2.f, muxy, c1) * fmaf(2.f, sgxy, c2);
    const float den = (m2 + c1) * (sgss + c2);
    const float s = num * __builtin_amdgcn_rcpf(den);
    return fminf(fmaxf(s, 0.f), 1.f);
  };

  auto body = [&](int it, int slot, bool dosub, bool doemit) {
    // stage row it (interleaved (x,y) so taps read as aligned float4)
    rowb[5 + 2*l] = make_float2(cur.m.x, cur.m.z);
    rowb[6 + 2*l] = make_float2(cur.m.y, cur.m.w);
    if (hval) rowb[hs] = cur.h;
    cur = nxt; nxt = nx2;
    nx2 = loadrow(it + 3);               // prefetch 3 rows ahead
    asm volatile("" ::: "memory");       // pin writes before reads

    // taps p=0..11 <-> local cols 2l-5 .. 2l+6 <-> slots 2l .. 2l+11 (16B-aligned)
    const float4* tb = (const float4*)(rowb + 2*l);
    float sx=0.f, sy=0.f, sxy=0.f, sss=0.f;
    float x0=0.f, y0=0.f, x11=0.f, y11=0.f;
    #pragma unroll
    for (int j = 0; j < 6; ++j) {
      const float4 v = tb[j];            // (x[p], y[p], x[p+1], y[p+1]), p=2j
      if (j == 0) { x0 = v.x; y0 = v.y; }
      sx += v.x; sy += v.y;
      sxy = fmaf(v.x, v.y, sxy);
      sss = fmaf(v.x, v.x, sss);
      sss = fmaf(v.y, v.y, sss);
      if (j < 5) {
        sx += v.z; sy += v.w;
        sxy = fmaf(v.z, v.w, sxy);
        sss = fmaf(v.z, v.z, sss);
        sss = fmaf(v.w, v.w, sss);
      } else { x11 = v.z; y11 = v.w; }
    }

    // col0 window = p0..p10 ; col1 = col0 - p0 + p11
    const float2 hx  = make_float2(sx,  sx - x0 + x11);
    const float2 hy  = make_float2(sy,  sy - y0 + y11);
    const float2 hxy = make_float2(sxy, fmaf(x11, y11, fmaf(-x0, y0, sxy)));
    const float2 hss = make_float2(sss,
        fmaf(x11, x11, fmaf(y11, y11, fmaf(-x0, x0, fmaf(-y0, y0, sss)))));

    if (dosub) {                         // drop row leaving the 11-row window
      const float4 o0 = ring0[slot][l];
      const float4 o1 = ring1[slot][l];
      vx.x  -= o0.x; vx.y  -= o1.x;
      vy.x  -= o0.y; vy.y  -= o1.y;
      vxy.x -= o0.z; vxy.y -= o1.z;
      vss.x -= o0.w; vss.y -= o1.w;
    }
    ring0[slot][l] = make_float4(hx.x, hy.x, hxy.x, hss.x);
    ring1[slot][l] = make_float4(hx.y, hy.y, hxy.y, hss.y);
    asm volatile("" ::: "memory");       // pin reads before next row's writes

    vx  = f2add(vx,  hx);  vy  = f2add(vy,  hy);
    vxy = f2add(vxy, hxy); vss = f2add(vss, hss);

    if (doemit) {
      acc += ssim1(vx.x, vy.x, vxy.x, vss.x);
      acc += ssim1(vx.y, vy.y, vxy.y, vss.y);
    }
  };

  // 74 input rows: warmup 11 (first emit at it=10), steady 5x11, tail 8
  #pragma unroll
  for (int u = 0; u < 11; ++u) body(u, u, false, u == 10);
  for (int g = 0; g < 5; ++g) {
    #pragma unroll
    for (int u = 0; u < 11; ++u) body(11 + 11*g + u, u, true, true);
  }
  #pragma unroll
  for (int u = 0; u < 8; ++u) body(66 + u, u, true, true);

  // wave reduction -> one atomic per wave (single-wave block, no LDS step)
  #pragma unroll
  for (int off = 32; off > 0; off >>= 1) acc += __shfl_down(acc, off, 64);
  if (l == 0) atomicAdd(&ws[b], acc);
}

__global__ void ssim_final(const float* __restrict__ ws, float* __restrict__ out) {
  const int i = threadIdx.x;
  if (i < NBATCH) out[i] = 1.0f - ws[i] * (1.0f / (float)(NCH*HH*WW));
}

extern "C" void kernel_launch(void* const* d_in, const int* in_sizes, int n_in,
                              void* d_out, int out_size, void* d_ws, size_t ws_size,
                              hipStream_t stream) {
  const float* pred = (const float*)d_in[0];
  const float* targ = (const float*)d_in[1];
  float* out = (float*)d_out;
  float* ws  = (float*)d_ws;
  hipMemsetAsync(ws, 0, NBATCH * sizeof(float), stream);
  ssim_main<<<dim3(NIMG*NCHUNK*NSTRIP), dim3(NT), 0, stream>>>(pred, targ, ws);
  ssim_final<<<dim3(1), dim3(64), 0, stream>>>(ws, out);
}